// Round 9
// baseline (1261.671 us; speedup 1.0000x reference)
//
#include <hip/hip_runtime.h>
#include <hip/hip_bf16.h>
#include <stdint.h>
#include <math.h>

// ---------------------------------------------------------------------------
// SymmetricRBM: CD loss, 10-step Gibbs, JAX-threefry-exact RNG.
// B=8192, V=H=1024. R8->R9: raw-asm pipelined GEMM K-loop:
//   s_waitcnt vmcnt(3) + s_barrier (inline asm, NOT __syncthreads) so the
//   2-iteration-deep staging prefetch stays in flight across the barrier --
//   the hipBLASLt pattern m97-style structures cannot express. Triple LDS
//   buffers are THREE DISTINCT __shared__ arrays so alias analysis doesn't
//   insert conservative vmcnt(0) before ds_reads. Tile 64x128xBK32, grid
//   1024 = exactly 4 blocks/CU, 36KB LDS/block, XOR-swizzled (conflict-free).
// ---------------------------------------------------------------------------

static constexpr int Bn = 8192;
static constexpr int Vn = 1024;
static constexpr int Hn = 1024;
static constexpr int KSTEPS = 10;

typedef _Float16 f16;
typedef f16   f16x4 __attribute__((ext_vector_type(4)));
typedef f16   f16x8 __attribute__((ext_vector_type(8)));
typedef float f32x4 __attribute__((ext_vector_type(4)));

#define GLOBAL_LOAD_LDS16(g, l)                                              \
  __builtin_amdgcn_global_load_lds(                                          \
      (const __attribute__((address_space(1))) uint32_t*)(g),                \
      (__attribute__((address_space(3))) uint32_t*)(l), 16, 0, 0)

// ------------------------- Threefry-2x32 (JAX-exact) -----------------------
__device__ __forceinline__ uint32_t rotl32(uint32_t x, int d) {
  return (x << d) | (x >> (32 - d));
}

__device__ __forceinline__ void tf2x32(uint32_t k0, uint32_t k1,
                                       uint32_t x0, uint32_t x1,
                                       uint32_t& o0, uint32_t& o1) {
  uint32_t k2 = k0 ^ k1 ^ 0x1BD11BDAu;
#define TFR(r) { x0 += x1; x1 = rotl32(x1, (r)); x1 ^= x0; }
  x0 += k0; x1 += k1;
  TFR(13) TFR(15) TFR(26) TFR(6)
  x0 += k1; x1 += k2 + 1u;
  TFR(17) TFR(29) TFR(16) TFR(24)
  x0 += k2; x1 += k0 + 2u;
  TFR(13) TFR(15) TFR(26) TFR(6)
  x0 += k0; x1 += k1 + 3u;
  TFR(17) TFR(29) TFR(16) TFR(24)
  x0 += k1; x1 += k2 + 4u;
  TFR(13) TFR(15) TFR(26) TFR(6)
  x0 += k2; x1 += k0 + 5u;
#undef TFR
  o0 = x0; o1 = x1;
}

__device__ __forceinline__ float rng_u01(uint2 key, uint32_t idx) {
  uint32_t o0, o1;
  tf2x32(key.x, key.y, 0u, idx, o0, o1);
  uint32_t bits = o0 ^ o1;
  return __uint_as_float((bits >> 9) | 0x3F800000u) - 1.0f;
}

// sampling-path sigmoid: keep libm precision (bit-exact chain vs reference)
__device__ __forceinline__ float sigmoidf_(float z) {
  return 1.0f / (1.0f + expf(-z));
}
// free-energy-only softplus: fast hw transcendentals (not on sampling path)
__device__ __forceinline__ float softplus_fast(float x) {
  return fmaxf(x, 0.f) + __logf(1.f + __expf(-fabsf(x)));
}

// ------------------------------- prep kernels ------------------------------
__global__ void prep_keys(const int* __restrict__ seedp, uint2* __restrict__ keys) {
  if (threadIdx.x != 0 || blockIdx.x != 0) return;
  uint32_t seed = (uint32_t)(*seedp);
  uint2 key = make_uint2(0u, seed);
  uint2 nk, kk;
  tf2x32(key.x, key.y, 0u, 0u, nk.x, nk.y);
  tf2x32(key.x, key.y, 0u, 1u, kk.x, kk.y);
  keys[0] = kk;   // k0
  key = nk;
  for (int s = 0; s < KSTEPS; ++s) {
    uint2 t0, t1, t2, t3;
    tf2x32(key.x, key.y, 0u, 0u, t0.x, t0.y);
    tf2x32(key.x, key.y, 0u, 1u, t1.x, t1.y);
    tf2x32(key.x, key.y, 0u, 2u, t2.x, t2.y);
    tf2x32(key.x, key.y, 0u, 3u, t3.x, t3.y);
    key = t0;
    keys[1 + 3*s] = t1;  // k1
    keys[2 + 3*s] = t2;  // k2
    keys[3 + 3*s] = t3;  // k3
  }
}

__global__ void colsum_k(const float* __restrict__ W, float* __restrict__ cs) {
  int h = blockIdx.x * 256 + threadIdx.x;
  float s = 0.f;
  for (int k = 0; k < Vn; ++k) s += W[(size_t)k * Hn + h];
  cs[h] = s;
}

__global__ void bsum_k(const float* __restrict__ bvec, float* __restrict__ bs) {
  __shared__ float sb[4];
  float s = 0.f;
  for (int i = threadIdx.x; i < Vn; i += 256) s += bvec[i];
  for (int off = 32; off > 0; off >>= 1) s += __shfl_down(s, off, 64);
  int wv = threadIdx.x >> 6, ln = threadIdx.x & 63;
  if (ln == 0) sb[wv] = s;
  __syncthreads();
  if (threadIdx.x == 0) bs[0] = sb[0] + sb[1] + sb[2] + sb[3];
}

// W -> f16 (row-major) and f16 transposed, LDS-tiled for coalesced stores
__global__ __launch_bounds__(256) void cast_W(
    const float* __restrict__ W, f16* __restrict__ Wf, f16* __restrict__ WTf) {
  __shared__ f16 tile[64][65];
  const int j0 = blockIdx.x * 64, i0 = blockIdx.y * 64;
  const int tx = threadIdx.x & 63, tg = threadIdx.x >> 6;   // 4 groups of 16 rows
#pragma unroll 4
  for (int rr = 0; rr < 16; ++rr) {
    const int row = tg * 16 + rr;
    float w = W[(size_t)(i0 + row) * Hn + j0 + tx];
    f16 hw = (f16)w;
    Wf[(size_t)(i0 + row) * Hn + j0 + tx] = hw;
    tile[row][tx] = hw;
  }
  __syncthreads();
#pragma unroll 4
  for (int rr = 0; rr < 16; ++rr) {
    const int row = tg * 16 + rr;
    WTf[(size_t)(j0 + row) * Vn + i0 + tx] = tile[tx][row];
  }
}

__global__ __launch_bounds__(256) void cast_v(
    const float* __restrict__ vd, f16* __restrict__ v) {
  const int idx = blockIdx.x * 256 + threadIdx.x;   // element-group of 4
  const float4 d = ((const float4*)vd)[idx];
  f16x4 o = { (f16)d.x, (f16)d.y, (f16)d.z, (f16)d.w };
  *(f16x4*)(v + (size_t)idx * 4) = o;
}

__global__ void u0_init(const uint2* __restrict__ keys, float* __restrict__ u) {
  int b = blockIdx.x * 256 + threadIdx.x;
  float r01 = rng_u01(keys[0], (uint32_t)b);
  u[b] = (r01 < 0.5f) ? 1.f : 0.f;
}

// -------------------- GEMM: asm-pipelined triple-buffer ---------------------
// C[m][n] = sum_k A[m][k]*B[n][k]; tile 64x128, BK=32, 256 thr (4 waves 2x2).
// Loop: waitcnt vmcnt(3); s_barrier; ds_read frag(s); stage(s+2); mfma.
// Stage loads for s+1,s+2 stay in flight across the barrier (3 per thread).
// LDS: 3 distinct buffers (alias-analysis separation), 12 KB each.
// Swizzle: 16B chunk c of row r stored at c^(r&3) -> staging line-coalesced,
// fragment ds_read_b128 8 lanes per 4-bank group = conflict-free.
template <int EPI>
__global__ __launch_bounds__(256, 4) void gemm_pl(
    const f16* __restrict__ A, const f16* __restrict__ Bm,
    float* __restrict__ outA, f16* __restrict__ outH,
    const float* __restrict__ u, const float* __restrict__ colsum,
    const float* __restrict__ cvec,
    const uint2* __restrict__ keys, int keyIdx)
{
  constexpr int N = 1024, K = 1024;
  __shared__ alignas(16) f16 SB0[6144];   // [A 64x32 | B 128x32] buf 0
  __shared__ alignas(16) f16 SB1[6144];   // buf 1
  __shared__ alignas(16) f16 SB2[6144];   // buf 2

  const int t = threadIdx.x, wave = t >> 6, lane = t & 63;
  const int l15 = lane & 15, quad = lane >> 4;
  const int m0 = blockIdx.x * 64;
  const int n0 = blockIdx.y * 128;
  const int wm = (wave >> 1) * 32, wn = (wave & 1) * 64;

  // staging source: slot p = wave*64+lane (A) / +j*256 (B); row r=p>>2,
  // global chunk c=(p&3)^(r&3)
  const int rA = wave * 16 + (lane >> 2);
  const int cA = (lane & 3) ^ ((lane >> 2) & 3);
  const f16* gA  = A  + (size_t)(m0 + rA) * K + cA * 8;
  const f16* gB0 = Bm + (size_t)(n0 + rA) * K + cA * 8;
  const f16* gB1 = gB0 + (size_t)64 * K;

  auto bufp = [&](int b) -> f16* { return (b == 0) ? SB0 : (b == 1) ? SB1 : SB2; };

  auto stage = [&](int b, int s) {
    f16* base = bufp(b);
    const int ko = s * 32;
    GLOBAL_LOAD_LDS16(gA  + ko, base + wave * 512);                 // A slots
    GLOBAL_LOAD_LDS16(gB0 + ko, base + 2048 + wave * 512);          // B j=0
    GLOBAL_LOAD_LDS16(gB1 + ko, base + 2048 + 2048 + wave * 512);   // B j=1
  };

  // fragment lane offsets (bytes): row*64 + (quad^(l15&3))*16
  const int fch = (quad ^ (l15 & 3)) * 16;
  const int offA = (wm + l15) * 64 + fch;          // + i*1024 imm
  const int offB = 4096 + (wn + l15) * 64 + fch;   // + nt*1024 imm

  stage(0, 0);
  stage(1, 1);

  f32x4 acc[2][4] = {};
#pragma unroll
  for (int s = 0; s < 32; ++s) {
    if (s == 31) { asm volatile("s_waitcnt vmcnt(0)\ns_barrier" ::: "memory"); }
    else         { asm volatile("s_waitcnt vmcnt(3)\ns_barrier" ::: "memory"); }
    const char* base = (const char*)bufp(s % 3);
    f16x8 af[2], bf[4];
#pragma unroll
    for (int i = 0; i < 2; ++i)
      af[i] = *(const f16x8*)(base + offA + i * 1024);
#pragma unroll
    for (int nt = 0; nt < 4; ++nt)
      bf[nt] = *(const f16x8*)(base + offB + nt * 1024);
    if (s + 2 < 32) stage((s + 2) % 3, s + 2);
#pragma unroll
    for (int nt = 0; nt < 4; ++nt) {
      acc[0][nt] = __builtin_amdgcn_mfma_f32_16x16x32_f16(af[0], bf[nt], acc[0][nt], 0, 0, 0);
      acc[1][nt] = __builtin_amdgcn_mfma_f32_16x16x32_f16(af[1], bf[nt], acc[1][nt], 0, 0, 0);
    }
  }

  // epilogue: C/D layout col = lane&15, row = quad*4 + reg   (m89/m91)
  if constexpr (EPI == 0) {
#pragma unroll
    for (int mt = 0; mt < 2; ++mt)
#pragma unroll
      for (int r = 0; r < 4; ++r) {
        const int gm = m0 + wm + mt * 16 + quad * 4 + r;
#pragma unroll
        for (int nt = 0; nt < 4; ++nt) {
          const int gn = n0 + wn + nt * 16 + l15;
          outA[(size_t)gm * N + gn] = acc[mt][nt][r];
        }
      }
  } else {
    const uint2 key = keys[keyIdx];
#pragma unroll
    for (int mt = 0; mt < 2; ++mt)
#pragma unroll
      for (int r = 0; r < 4; ++r) {
        const int gm  = m0 + wm + mt * 16 + quad * 4 + r;
        const float ubr = u[gm];
#pragma unroll
        for (int nt = 0; nt < 4; ++nt) {
          const int gn = n0 + wn + nt * 16 + l15;
          float val = acc[mt][nt][r];
          float z = (ubr > 0.5f) ? val : (colsum[gn] - val);   // v_branch @ W
          z += cvec[gn];
          float p   = sigmoidf_(z);
          float r01 = rng_u01(key, (uint32_t)(gm * N + gn));
          outH[(size_t)gm * N + gn] = (f16)((r01 < p) ? 1.0f : 0.0f);
        }
      }
  }
}

// ---------------- fused per-row: dE -> u_new -> v_new ----------------------
__global__ __launch_bounds__(256) void row_uv(
    const float* __restrict__ a, const f16* __restrict__ v,
    const float* __restrict__ bvec, const float* __restrict__ bsum,
    const uint2* __restrict__ keys, int kU, int kV,
    f16* __restrict__ vout)
{
  __shared__ float s1[4], s2[4], s3[4];
  __shared__ float su;
  const int row = blockIdx.x;
  const int t = threadIdx.x;
  const float4 av = ((const float4*)(a + (size_t)row * Vn))[t];
  const float4 bv = ((const float4*)bvec)[t];
  const f16x4  vo = *(const f16x4*)(v + (size_t)row * Vn + t * 4);

  float asum = av.x + av.y + av.z + av.w;
  float va = (float)vo[0]*av.x + (float)vo[1]*av.y + (float)vo[2]*av.z + (float)vo[3]*av.w;
  float vb = (float)vo[0]*bv.x + (float)vo[1]*bv.y + (float)vo[2]*bv.z + (float)vo[3]*bv.w;
#pragma unroll
  for (int off = 32; off > 0; off >>= 1) {
    asum += __shfl_down(asum, off, 64);
    va   += __shfl_down(va,   off, 64);
    vb   += __shfl_down(vb,   off, 64);
  }
  const int wv = t >> 6, ln = t & 63;
  if (ln == 0) { s1[wv] = asum; s2[wv] = va; s3[wv] = vb; }
  __syncthreads();
  if (t == 0) {
    asum = s1[0] + s1[1] + s1[2] + s1[3];
    va   = s2[0] + s2[1] + s2[2] + s2[3];
    vb   = s3[0] + s3[1] + s3[2] + s3[3];
    float dE  = -bsum[0] - asum + 2.f * vb + 2.f * va;
    float p   = sigmoidf_(dE);
    float r01 = rng_u01(keys[kU], (uint32_t)row);
    su = (r01 < p) ? 1.f : 0.f;
  }
  __syncthreads();
  const float un = su;
  const uint2 kv = keys[kV];
  float az[4] = { av.x, av.y, av.z, av.w };
  float bz[4] = { bv.x, bv.y, bv.z, bv.w };
  f16x4 vn;
#pragma unroll
  for (int j = 0; j < 4; ++j) {
    float p   = sigmoidf_(az[j] + bz[j]);
    float r01 = rng_u01(kv, (uint32_t)(row * Vn + t * 4 + j));
    float x   = (r01 < p) ? 1.f : 0.f;
    vn[j] = (f16)((un > 0.5f) ? x : 1.f - x);
  }
  *(f16x4*)(vout + (size_t)row * Vn + t * 4) = vn;
}

// ------------------------------ free energy --------------------------------
__global__ __launch_bounds__(256) void fe_rows(
    const float* __restrict__ a, const f16* __restrict__ v,
    const float* __restrict__ bvec, const float* __restrict__ cvec,
    const float* __restrict__ colsum, const float* __restrict__ bsum,
    float* __restrict__ Fout)
{
  __shared__ float s1[4], s2[4], s3[4];
  const int row = blockIdx.x;
  const int t = threadIdx.x;
  const float4 m4 = ((const float4*)(a + (size_t)row * Hn))[t];
  const float4 c4 = ((const float4*)cvec)[t];
  const float4 w4 = ((const float4*)colsum)[t];
  const float4 b4 = ((const float4*)bvec)[t];
  const f16x4  v4 = *(const f16x4*)(v + (size_t)row * Vn + t * 4);

  float mm[4] = { m4.x, m4.y, m4.z, m4.w };
  float cc[4] = { c4.x, c4.y, c4.z, c4.w };
  float ww[4] = { w4.x, w4.y, w4.z, w4.w };
  float bb[4] = { b4.x, b4.y, b4.z, b4.w };
  float S1 = 0.f, S2 = 0.f, vb = 0.f;
#pragma unroll
  for (int j = 0; j < 4; ++j) {
    S1 += softplus_fast(mm[j] + cc[j]);
    S2 += softplus_fast(ww[j] - mm[j] + cc[j]);
    vb += (float)v4[j] * bb[j];
  }
#pragma unroll
  for (int off = 32; off > 0; off >>= 1) {
    S1 += __shfl_down(S1, off, 64);
    S2 += __shfl_down(S2, off, 64);
    vb += __shfl_down(vb, off, 64);
  }
  const int wv = t >> 6, ln = t & 63;
  if (ln == 0) { s1[wv] = S1; s2[wv] = S2; s3[wv] = vb; }
  __syncthreads();
  if (t == 0) {
    S1 = s1[0] + s1[1] + s1[2] + s1[3];
    S2 = s2[0] + s2[1] + s2[2] + s2[3];
    vb = s3[0] + s3[1] + s3[2] + s3[3];
    float negn = vb - S1;
    float negf = (bsum[0] - vb) - S2;
    float mx = fmaxf(negn, negf);
    Fout[row] = -(mx + logf(expf(negn - mx) + expf(negf - mx)));
  }
}

__global__ __launch_bounds__(256) void finalize_k(
    const float* __restrict__ Fd, const float* __restrict__ Fm, float* __restrict__ out)
{
  __shared__ double sb[8];
  double sd = 0.0, sm = 0.0;
  for (int i = threadIdx.x; i < Bn; i += 256) { sd += (double)Fd[i]; sm += (double)Fm[i]; }
  for (int off = 32; off > 0; off >>= 1) { sd += __shfl_down(sd, off, 64); sm += __shfl_down(sm, off, 64); }
  const int wv = threadIdx.x >> 6, ln = threadIdx.x & 63;
  if (ln == 0) { sb[wv] = sd; sb[4 + wv] = sm; }
  __syncthreads();
  if (threadIdx.x == 0) {
    sd = sb[0] + sb[1] + sb[2] + sb[3];
    sm = sb[4] + sb[5] + sb[6] + sb[7];
    out[0] = (float)((sd - sm) / (double)Bn);
  }
}

// ------------------------------ launch glue --------------------------------
extern "C" void kernel_launch(void* const* d_in, const int* in_sizes, int n_in,
                              void* d_out, int out_size, void* d_ws, size_t ws_size,
                              hipStream_t stream) {
  const float* v_data = (const float*)d_in[0];
  const float* W      = (const float*)d_in[1];
  const float* bvec   = (const float*)d_in[2];
  const float* cvec   = (const float*)d_in[3];
  const int*   seedp  = (const int*)d_in[4];
  float* out = (float*)d_out;

  char* ws = (char*)d_ws;
  size_t off = 0;
  auto alloc = [&](size_t bytes) -> void* {
    void* p = ws + off;
    off += (bytes + 255) & ~(size_t)255;
    return p;
  };
  f16*   v    = (f16*)alloc((size_t)Bn * Vn * 2);     // 16 MB
  f16*   h    = (f16*)alloc((size_t)Bn * Hn * 2);     // 16 MB
  float* a    = (float*)alloc((size_t)Bn * Vn * 4);   // 32 MB
  f16*   Wf   = (f16*)alloc((size_t)Vn * Hn * 2);     // 2 MB  [V][H]
  f16*   WTf  = (f16*)alloc((size_t)Vn * Hn * 2);     // 2 MB  [H][V]
  float* colsum = (float*)alloc(Hn * 4);
  float* bsum   = (float*)alloc(256);
  uint2* keys   = (uint2*)alloc(64 * sizeof(uint2));
  float* u      = (float*)alloc(Bn * 4);
  float* Fd     = (float*)alloc(Bn * 4);
  float* Fm     = (float*)alloc(Bn * 4);
  (void)ws_size; (void)in_sizes; (void)n_in; (void)out_size;

  prep_keys<<<1, 64, 0, stream>>>(seedp, keys);
  colsum_k<<<Hn / 256, 256, 0, stream>>>(W, colsum);
  bsum_k<<<1, 256, 0, stream>>>(bvec, bsum);
  cast_W<<<dim3(Hn / 64, Vn / 64), 256, 0, stream>>>(W, Wf, WTf);
  cast_v<<<(Bn * Vn / 4) / 256, 256, 0, stream>>>(v_data, v);
  u0_init<<<Bn / 256, 256, 0, stream>>>(keys, u);

  dim3 gg(Bn / 64, Hn / 128);   // 128 x 8 = 1024 blocks = exactly 4/CU

  // F(v_data): a = v_data @ W
  gemm_pl<0><<<gg, 256, 0, stream>>>(v, WTf, a,
                                     nullptr, nullptr, nullptr, nullptr, nullptr, 0);
  fe_rows<<<Bn, 256, 0, stream>>>(a, v, bvec, cvec, colsum, bsum, Fd);

  for (int s = 0; s < KSTEPS; ++s) {
    // h = Bern(sigmoid(v_branch @ W + c)), fused threefry epilogue
    gemm_pl<1><<<gg, 256, 0, stream>>>(v, WTf, nullptr,
                                       h, u, colsum, cvec, keys, 1 + 3 * s);
    // a = h @ W^T
    gemm_pl<0><<<gg, 256, 0, stream>>>(h, Wf, a,
                                       nullptr, nullptr, nullptr, nullptr, nullptr, 0);
    // dE -> u_new -> v_new (fused)
    row_uv<<<Bn, 256, 0, stream>>>(a, v, bvec, bsum, keys, 2 + 3 * s, 3 + 3 * s, v);
  }

  // F(v_model)
  gemm_pl<0><<<gg, 256, 0, stream>>>(v, WTf, a,
                                     nullptr, nullptr, nullptr, nullptr, nullptr, 0);
  fe_rows<<<Bn, 256, 0, stream>>>(a, v, bvec, cvec, colsum, bsum, Fm);

  finalize_k<<<1, 256, 0, stream>>>(Fd, Fm, out);
}

// Round 10
// 1146.918 us; speedup vs baseline: 1.1001x; 1.1001x over previous
//
#include <hip/hip_runtime.h>
#include <hip/hip_bf16.h>
#include <stdint.h>
#include <math.h>

// ---------------------------------------------------------------------------
// SymmetricRBM: CD loss, 10-step Gibbs, JAX-threefry-exact RNG.
// B=8192, V=H=1024. R9->R10: PRODUCER-CONSUMER wave specialization.
//   Block = 320 thr: waves 0-3 consume (64x64 MFMA tiles), wave 4 produces
//   (global_load_lds only). Raw s_barrier (no vmcnt drain); producer uses
//   s_waitcnt vmcnt(16) so loads for iter s+2 stay in flight across barriers;
//   consumer waves never wait on vmcnt at all. Triple-buffer LDS 3x16KB.
//   Swizzle: phys 16B-chunk = logical ^ ((row>>1)&3) -- the R2/R3-proven
//   mapping (0 conflicts measured); R9's (row&3) variant was 4-way-conflicted.
//   K-order identical to prior rounds -> chain stays bit-exact (absmax 0.0).
// ---------------------------------------------------------------------------

static constexpr int Bn = 8192;
static constexpr int Vn = 1024;
static constexpr int Hn = 1024;
static constexpr int KSTEPS = 10;

typedef _Float16 f16;
typedef f16   f16x4 __attribute__((ext_vector_type(4)));
typedef f16   f16x8 __attribute__((ext_vector_type(8)));
typedef float f32x4 __attribute__((ext_vector_type(4)));

#define GLOBAL_LOAD_LDS16(g, l)                                              \
  __builtin_amdgcn_global_load_lds(                                          \
      (const __attribute__((address_space(1))) uint32_t*)(g),                \
      (__attribute__((address_space(3))) uint32_t*)(l), 16, 0, 0)

// ------------------------- Threefry-2x32 (JAX-exact) -----------------------
__device__ __forceinline__ uint32_t rotl32(uint32_t x, int d) {
  return (x << d) | (x >> (32 - d));
}

__device__ __forceinline__ void tf2x32(uint32_t k0, uint32_t k1,
                                       uint32_t x0, uint32_t x1,
                                       uint32_t& o0, uint32_t& o1) {
  uint32_t k2 = k0 ^ k1 ^ 0x1BD11BDAu;
#define TFR(r) { x0 += x1; x1 = rotl32(x1, (r)); x1 ^= x0; }
  x0 += k0; x1 += k1;
  TFR(13) TFR(15) TFR(26) TFR(6)
  x0 += k1; x1 += k2 + 1u;
  TFR(17) TFR(29) TFR(16) TFR(24)
  x0 += k2; x1 += k0 + 2u;
  TFR(13) TFR(15) TFR(26) TFR(6)
  x0 += k0; x1 += k1 + 3u;
  TFR(17) TFR(29) TFR(16) TFR(24)
  x0 += k1; x1 += k2 + 4u;
  TFR(13) TFR(15) TFR(26) TFR(6)
  x0 += k2; x1 += k0 + 5u;
#undef TFR
  o0 = x0; o1 = x1;
}

__device__ __forceinline__ float rng_u01(uint2 key, uint32_t idx) {
  uint32_t o0, o1;
  tf2x32(key.x, key.y, 0u, idx, o0, o1);
  uint32_t bits = o0 ^ o1;
  return __uint_as_float((bits >> 9) | 0x3F800000u) - 1.0f;
}

// sampling-path sigmoid: keep libm precision (bit-exact chain vs reference)
__device__ __forceinline__ float sigmoidf_(float z) {
  return 1.0f / (1.0f + expf(-z));
}
// free-energy-only softplus: fast hw transcendentals (not on sampling path)
__device__ __forceinline__ float softplus_fast(float x) {
  return fmaxf(x, 0.f) + __logf(1.f + __expf(-fabsf(x)));
}

// ------------------------------- prep kernels ------------------------------
__global__ void prep_keys(const int* __restrict__ seedp, uint2* __restrict__ keys) {
  if (threadIdx.x != 0 || blockIdx.x != 0) return;
  uint32_t seed = (uint32_t)(*seedp);
  uint2 key = make_uint2(0u, seed);
  uint2 nk, kk;
  tf2x32(key.x, key.y, 0u, 0u, nk.x, nk.y);
  tf2x32(key.x, key.y, 0u, 1u, kk.x, kk.y);
  keys[0] = kk;   // k0
  key = nk;
  for (int s = 0; s < KSTEPS; ++s) {
    uint2 t0, t1, t2, t3;
    tf2x32(key.x, key.y, 0u, 0u, t0.x, t0.y);
    tf2x32(key.x, key.y, 0u, 1u, t1.x, t1.y);
    tf2x32(key.x, key.y, 0u, 2u, t2.x, t2.y);
    tf2x32(key.x, key.y, 0u, 3u, t3.x, t3.y);
    key = t0;
    keys[1 + 3*s] = t1;  // k1
    keys[2 + 3*s] = t2;  // k2
    keys[3 + 3*s] = t3;  // k3
  }
}

__global__ void colsum_k(const float* __restrict__ W, float* __restrict__ cs) {
  int h = blockIdx.x * 256 + threadIdx.x;
  float s = 0.f;
  for (int k = 0; k < Vn; ++k) s += W[(size_t)k * Hn + h];
  cs[h] = s;
}

__global__ void bsum_k(const float* __restrict__ bvec, float* __restrict__ bs) {
  __shared__ float sb[4];
  float s = 0.f;
  for (int i = threadIdx.x; i < Vn; i += 256) s += bvec[i];
  for (int off = 32; off > 0; off >>= 1) s += __shfl_down(s, off, 64);
  int wv = threadIdx.x >> 6, ln = threadIdx.x & 63;
  if (ln == 0) sb[wv] = s;
  __syncthreads();
  if (threadIdx.x == 0) bs[0] = sb[0] + sb[1] + sb[2] + sb[3];
}

// W -> f16 (row-major) and f16 transposed, LDS-tiled for coalesced stores
__global__ __launch_bounds__(256) void cast_W(
    const float* __restrict__ W, f16* __restrict__ Wf, f16* __restrict__ WTf) {
  __shared__ f16 tile[64][65];
  const int j0 = blockIdx.x * 64, i0 = blockIdx.y * 64;
  const int tx = threadIdx.x & 63, tg = threadIdx.x >> 6;   // 4 groups of 16 rows
#pragma unroll 4
  for (int rr = 0; rr < 16; ++rr) {
    const int row = tg * 16 + rr;
    float w = W[(size_t)(i0 + row) * Hn + j0 + tx];
    f16 hw = (f16)w;
    Wf[(size_t)(i0 + row) * Hn + j0 + tx] = hw;
    tile[row][tx] = hw;
  }
  __syncthreads();
#pragma unroll 4
  for (int rr = 0; rr < 16; ++rr) {
    const int row = tg * 16 + rr;
    WTf[(size_t)(j0 + row) * Vn + i0 + tx] = tile[tx][row];
  }
}

__global__ __launch_bounds__(256) void cast_v(
    const float* __restrict__ vd, f16* __restrict__ v) {
  const int idx = blockIdx.x * 256 + threadIdx.x;   // element-group of 4
  const float4 d = ((const float4*)vd)[idx];
  f16x4 o = { (f16)d.x, (f16)d.y, (f16)d.z, (f16)d.w };
  *(f16x4*)(v + (size_t)idx * 4) = o;
}

__global__ void u0_init(const uint2* __restrict__ keys, float* __restrict__ u) {
  int b = blockIdx.x * 256 + threadIdx.x;
  float r01 = rng_u01(keys[0], (uint32_t)b);
  u[b] = (r01 < 0.5f) ? 1.f : 0.f;
}

// ------------------- GEMM: producer-consumer specialization -----------------
// C[m][n] = sum_k A[m][k]*B[n][k]. Tile 128x128, BK=32, 32 iters.
// Waves 0-3: consumers (64x64 each, 2x2). Wave 4: producer (16 loads/iter).
// Per iter: producer issues loads(s+2)->buf[(s+2)%3], waits vmcnt(16)
// (= loads(s+1) landed); consumers read buf[s%3] + MFMA + lgkmcnt(0);
// one raw s_barrier publishes buf[(s+1)%3]. No vmcnt(0) drain ever
// (single vmcnt(0) at s>=30 tail only).
template <int EPI>
__global__ __launch_bounds__(320, 4) void gemm_pc(
    const f16* __restrict__ A, const f16* __restrict__ Bm,
    float* __restrict__ outA, f16* __restrict__ outH,
    const float* __restrict__ u, const float* __restrict__ colsum,
    const float* __restrict__ cvec,
    const uint2* __restrict__ keys, int keyIdx)
{
  constexpr int N = 1024, K = 1024, BK = 32;
  __shared__ alignas(16) f16 Buf[3][8192];   // per buf: A [0,4096), B [4096,8192)

  const int t = threadIdx.x, wave = t >> 6, lane = t & 63;
  const int l15 = lane & 15, quad = lane >> 4;
  const int m0 = blockIdx.x * 128, n0 = blockIdx.y * 128;

  if (wave == 4) {
    // ---- producer ----
    // instr j covers rows j*16 + (lane>>2); lane fetches global 16B-chunk
    // (lane&3) ^ ((lane>>3)&3)  [= phys (lane&3) ^ swizzle key (row>>1)&3]
    const int rr  = lane >> 2;
    const int gch = (lane & 3) ^ ((lane >> 3) & 3);
    const f16* pa = A  + (size_t)(m0 + rr) * K + gch * 8;
    const f16* pb = Bm + (size_t)(n0 + rr) * K + gch * 8;
    auto stage = [&](int b, int s) {
      const int ko = s * BK;
#pragma unroll
      for (int j = 0; j < 8; ++j) {
        GLOBAL_LOAD_LDS16(pa + (size_t)j * 16 * K + ko, &Buf[b][j * 512]);
        GLOBAL_LOAD_LDS16(pb + (size_t)j * 16 * K + ko, &Buf[b][4096 + j * 512]);
      }
    };
    stage(0, 0);
    stage(1, 1);
    asm volatile("s_waitcnt vmcnt(16)" ::: "memory");   // loads(0) landed
    asm volatile("s_barrier" ::: "memory");
#pragma unroll
    for (int s = 0; s < 32; ++s) {
      if (s + 2 < 32) {
        stage((s + 2) % 3, s + 2);
        asm volatile("s_waitcnt vmcnt(16)" ::: "memory");  // loads(s+1) landed
      } else {
        asm volatile("s_waitcnt vmcnt(0)" ::: "memory");   // tail drain
      }
      asm volatile("s_barrier" ::: "memory");
    }
    return;   // producer exits; no further barriers anywhere
  }

  // ---- consumers ----
  const int wm  = (wave >> 1) * 64, wn = (wave & 1) * 64;
  const int swz = (l15 >> 1) & 3;                      // (row>>1)&3, row=...+l15
  const int oA  = (wm + l15) * BK + (quad ^ swz) * 8;  // + i*16*BK (imm)
  const int oB  = 4096 + (wn + l15) * BK + (quad ^ swz) * 8;

  f32x4 acc[4][4] = {};
  asm volatile("s_barrier" ::: "memory");
#pragma unroll
  for (int s = 0; s < 32; ++s) {
    const f16* base = Buf[s % 3];
    f16x8 af[4], bf[4];
#pragma unroll
    for (int i = 0; i < 4; ++i) {
      af[i] = *(const f16x8*)(base + oA + i * 16 * BK);
      bf[i] = *(const f16x8*)(base + oB + i * 16 * BK);
    }
#pragma unroll
    for (int mt = 0; mt < 4; ++mt)
#pragma unroll
      for (int nt = 0; nt < 4; ++nt)
        acc[mt][nt] = __builtin_amdgcn_mfma_f32_16x16x32_f16(af[mt], bf[nt], acc[mt][nt], 0, 0, 0);
    asm volatile("s_waitcnt lgkmcnt(0)" ::: "memory");  // reads done before WAR
    asm volatile("s_barrier" ::: "memory");
  }

  // epilogue: C/D layout col = lane&15, row = quad*4 + reg   (m89/m91)
  if constexpr (EPI == 0) {
#pragma unroll
    for (int mt = 0; mt < 4; ++mt)
#pragma unroll
      for (int r = 0; r < 4; ++r) {
        const int gm = m0 + wm + mt * 16 + quad * 4 + r;
#pragma unroll
        for (int nt = 0; nt < 4; ++nt) {
          const int gn = n0 + wn + nt * 16 + l15;
          outA[(size_t)gm * N + gn] = acc[mt][nt][r];
        }
      }
  } else {
    const uint2 key = keys[keyIdx];
#pragma unroll
    for (int mt = 0; mt < 4; ++mt)
#pragma unroll
      for (int r = 0; r < 4; ++r) {
        const int gm  = m0 + wm + mt * 16 + quad * 4 + r;
        const float ubr = u[gm];
#pragma unroll
        for (int nt = 0; nt < 4; ++nt) {
          const int gn = n0 + wn + nt * 16 + l15;
          float val = acc[mt][nt][r];
          float z = (ubr > 0.5f) ? val : (colsum[gn] - val);   // v_branch @ W
          z += cvec[gn];
          float p   = sigmoidf_(z);
          float r01 = rng_u01(key, (uint32_t)(gm * N + gn));
          outH[(size_t)gm * N + gn] = (f16)((r01 < p) ? 1.0f : 0.0f);
        }
      }
  }
}

// ---------------- fused per-row: dE -> u_new -> v_new ----------------------
__global__ __launch_bounds__(256) void row_uv(
    const float* __restrict__ a, const f16* __restrict__ v,
    const float* __restrict__ bvec, const float* __restrict__ bsum,
    const uint2* __restrict__ keys, int kU, int kV,
    f16* __restrict__ vout)
{
  __shared__ float s1[4], s2[4], s3[4];
  __shared__ float su;
  const int row = blockIdx.x;
  const int t = threadIdx.x;
  const float4 av = ((const float4*)(a + (size_t)row * Vn))[t];
  const float4 bv = ((const float4*)bvec)[t];
  const f16x4  vo = *(const f16x4*)(v + (size_t)row * Vn + t * 4);

  float asum = av.x + av.y + av.z + av.w;
  float va = (float)vo[0]*av.x + (float)vo[1]*av.y + (float)vo[2]*av.z + (float)vo[3]*av.w;
  float vb = (float)vo[0]*bv.x + (float)vo[1]*bv.y + (float)vo[2]*bv.z + (float)vo[3]*bv.w;
#pragma unroll
  for (int off = 32; off > 0; off >>= 1) {
    asum += __shfl_down(asum, off, 64);
    va   += __shfl_down(va,   off, 64);
    vb   += __shfl_down(vb,   off, 64);
  }
  const int wv = t >> 6, ln = t & 63;
  if (ln == 0) { s1[wv] = asum; s2[wv] = va; s3[wv] = vb; }
  __syncthreads();
  if (t == 0) {
    asum = s1[0] + s1[1] + s1[2] + s1[3];
    va   = s2[0] + s2[1] + s2[2] + s2[3];
    vb   = s3[0] + s3[1] + s3[2] + s3[3];
    float dE  = -bsum[0] - asum + 2.f * vb + 2.f * va;
    float p   = sigmoidf_(dE);
    float r01 = rng_u01(keys[kU], (uint32_t)row);
    su = (r01 < p) ? 1.f : 0.f;
  }
  __syncthreads();
  const float un = su;
  const uint2 kv = keys[kV];
  float az[4] = { av.x, av.y, av.z, av.w };
  float bz[4] = { bv.x, bv.y, bv.z, bv.w };
  f16x4 vn;
#pragma unroll
  for (int j = 0; j < 4; ++j) {
    float p   = sigmoidf_(az[j] + bz[j]);
    float r01 = rng_u01(kv, (uint32_t)(row * Vn + t * 4 + j));
    float x   = (r01 < p) ? 1.f : 0.f;
    vn[j] = (f16)((un > 0.5f) ? x : 1.f - x);
  }
  *(f16x4*)(vout + (size_t)row * Vn + t * 4) = vn;
}

// ------------------------------ free energy --------------------------------
__global__ __launch_bounds__(256) void fe_rows(
    const float* __restrict__ a, const f16* __restrict__ v,
    const float* __restrict__ bvec, const float* __restrict__ cvec,
    const float* __restrict__ colsum, const float* __restrict__ bsum,
    float* __restrict__ Fout)
{
  __shared__ float s1[4], s2[4], s3[4];
  const int row = blockIdx.x;
  const int t = threadIdx.x;
  const float4 m4 = ((const float4*)(a + (size_t)row * Hn))[t];
  const float4 c4 = ((const float4*)cvec)[t];
  const float4 w4 = ((const float4*)colsum)[t];
  const float4 b4 = ((const float4*)bvec)[t];
  const f16x4  v4 = *(const f16x4*)(v + (size_t)row * Vn + t * 4);

  float mm[4] = { m4.x, m4.y, m4.z, m4.w };
  float cc[4] = { c4.x, c4.y, c4.z, c4.w };
  float ww[4] = { w4.x, w4.y, w4.z, w4.w };
  float bb[4] = { b4.x, b4.y, b4.z, b4.w };
  float S1 = 0.f, S2 = 0.f, vb = 0.f;
#pragma unroll
  for (int j = 0; j < 4; ++j) {
    S1 += softplus_fast(mm[j] + cc[j]);
    S2 += softplus_fast(ww[j] - mm[j] + cc[j]);
    vb += (float)v4[j] * bb[j];
  }
#pragma unroll
  for (int off = 32; off > 0; off >>= 1) {
    S1 += __shfl_down(S1, off, 64);
    S2 += __shfl_down(S2, off, 64);
    vb += __shfl_down(vb, off, 64);
  }
  const int wv = t >> 6, ln = t & 63;
  if (ln == 0) { s1[wv] = S1; s2[wv] = S2; s3[wv] = vb; }
  __syncthreads();
  if (t == 0) {
    S1 = s1[0] + s1[1] + s1[2] + s1[3];
    S2 = s2[0] + s2[1] + s2[2] + s2[3];
    vb = s3[0] + s3[1] + s3[2] + s3[3];
    float negn = vb - S1;
    float negf = (bsum[0] - vb) - S2;
    float mx = fmaxf(negn, negf);
    Fout[row] = -(mx + logf(expf(negn - mx) + expf(negf - mx)));
  }
}

__global__ __launch_bounds__(256) void finalize_k(
    const float* __restrict__ Fd, const float* __restrict__ Fm, float* __restrict__ out)
{
  __shared__ double sb[8];
  double sd = 0.0, sm = 0.0;
  for (int i = threadIdx.x; i < Bn; i += 256) { sd += (double)Fd[i]; sm += (double)Fm[i]; }
  for (int off = 32; off > 0; off >>= 1) { sd += __shfl_down(sd, off, 64); sm += __shfl_down(sm, off, 64); }
  const int wv = threadIdx.x >> 6, ln = threadIdx.x & 63;
  if (ln == 0) { sb[wv] = sd; sb[4 + wv] = sm; }
  __syncthreads();
  if (threadIdx.x == 0) {
    sd = sb[0] + sb[1] + sb[2] + sb[3];
    sm = sb[4] + sb[5] + sb[6] + sb[7];
    out[0] = (float)((sd - sm) / (double)Bn);
  }
}

// ------------------------------ launch glue --------------------------------
extern "C" void kernel_launch(void* const* d_in, const int* in_sizes, int n_in,
                              void* d_out, int out_size, void* d_ws, size_t ws_size,
                              hipStream_t stream) {
  const float* v_data = (const float*)d_in[0];
  const float* W      = (const float*)d_in[1];
  const float* bvec   = (const float*)d_in[2];
  const float* cvec   = (const float*)d_in[3];
  const int*   seedp  = (const int*)d_in[4];
  float* out = (float*)d_out;

  char* ws = (char*)d_ws;
  size_t off = 0;
  auto alloc = [&](size_t bytes) -> void* {
    void* p = ws + off;
    off += (bytes + 255) & ~(size_t)255;
    return p;
  };
  f16*   v    = (f16*)alloc((size_t)Bn * Vn * 2);     // 16 MB
  f16*   h    = (f16*)alloc((size_t)Bn * Hn * 2);     // 16 MB
  float* a    = (float*)alloc((size_t)Bn * Vn * 4);   // 32 MB
  f16*   Wf   = (f16*)alloc((size_t)Vn * Hn * 2);     // 2 MB  [V][H]
  f16*   WTf  = (f16*)alloc((size_t)Vn * Hn * 2);     // 2 MB  [H][V]
  float* colsum = (float*)alloc(Hn * 4);
  float* bsum   = (float*)alloc(256);
  uint2* keys   = (uint2*)alloc(64 * sizeof(uint2));
  float* u      = (float*)alloc(Bn * 4);
  float* Fd     = (float*)alloc(Bn * 4);
  float* Fm     = (float*)alloc(Bn * 4);
  (void)ws_size; (void)in_sizes; (void)n_in; (void)out_size;

  prep_keys<<<1, 64, 0, stream>>>(seedp, keys);
  colsum_k<<<Hn / 256, 256, 0, stream>>>(W, colsum);
  bsum_k<<<1, 256, 0, stream>>>(bvec, bsum);
  cast_W<<<dim3(Hn / 64, Vn / 64), 256, 0, stream>>>(W, Wf, WTf);
  cast_v<<<(Bn * Vn / 4) / 256, 256, 0, stream>>>(v_data, v);
  u0_init<<<Bn / 256, 256, 0, stream>>>(keys, u);

  dim3 gg(Bn / 128, Hn / 128);   // 64 x 8 = 512 blocks, 320 thr each

  // F(v_data): a = v_data @ W
  gemm_pc<0><<<gg, 320, 0, stream>>>(v, WTf, a,
                                     nullptr, nullptr, nullptr, nullptr, nullptr, 0);
  fe_rows<<<Bn, 256, 0, stream>>>(a, v, bvec, cvec, colsum, bsum, Fd);

  for (int s = 0; s < KSTEPS; ++s) {
    // h = Bern(sigmoid(v_branch @ W + c)), fused threefry epilogue
    gemm_pc<1><<<gg, 320, 0, stream>>>(v, WTf, nullptr,
                                       h, u, colsum, cvec, keys, 1 + 3 * s);
    // a = h @ W^T
    gemm_pc<0><<<gg, 320, 0, stream>>>(h, Wf, a,
                                       nullptr, nullptr, nullptr, nullptr, nullptr, 0);
    // dE -> u_new -> v_new (fused)
    row_uv<<<Bn, 256, 0, stream>>>(a, v, bvec, bsum, keys, 2 + 3 * s, 3 + 3 * s, v);
  }

  // F(v_model)
  gemm_pc<0><<<gg, 320, 0, stream>>>(v, WTf, a,
                                     nullptr, nullptr, nullptr, nullptr, nullptr, 0);
  fe_rows<<<Bn, 256, 0, stream>>>(a, v, bvec, cvec, colsum, bsum, Fm);

  finalize_k<<<1, 256, 0, stream>>>(Fd, Fm, out);
}